// Round 22
// baseline (94.980 us; speedup 1.0000x reference)
//
#include <hip/hip_runtime.h>
#include <hip/hip_bf16.h>

typedef unsigned int u32;
typedef unsigned short u16;
typedef float f32x2 __attribute__((ext_vector_type(2)));
typedef float f32x4 __attribute__((ext_vector_type(4)));
using bf16x8 = __attribute__((ext_vector_type(8))) short;   // MFMA A/B frag (4 VGPRs)
using f32x4v = __attribute__((ext_vector_type(4))) float;   // MFMA C/D frag

#define DEVINL __device__ __forceinline__

// Problem constants: B=8, C=64, D=128, H=128, W=128
constexpr int LDS_AB = 65536;          // k_A/k_B: bufA(32K)+bufB(32K), [128][256B] each
constexpr int XS = 132;                // k_final transpose staging stride (u16)
constexpr int LDS_X = 128 * XS * 2;    // 33792

DEVINL float bf2f(u16 u) { union { u32 i; float f; } v; v.i = ((u32)u) << 16; return v.f; }
DEVINL float bf2f_lo(u32 u) { union { u32 i; float f; } v; v.i = u << 16; return v.f; }
DEVINL float bf2f_hi(u32 u) { union { u32 i; float f; } v; v.i = u & 0xffff0000u; return v.f; }
DEVINL u16 f2bf(float f) {
  __hip_bfloat16 h = __float2bfloat16(f);
  u16 r; __builtin_memcpy(&r, &h, 2); return r;
}
DEVINL u32 pack2(float a, float b) { return (u32)f2bf(a) | ((u32)f2bf(b) << 16); }

// ---------------- P0: A=tanh(A_param), Mrow[dir][c][d] bf16, beff, Wi_bf ----------------
__global__ __launch_bounds__(256) void k_pre(
    const float* __restrict__ Wf, const float* __restrict__ Wo,
    const float* __restrict__ bf_, const float* __restrict__ bo,
    const float* __restrict__ A_param, const float* __restrict__ Wi,
    float* __restrict__ A_t, float* __restrict__ beff,
    u16* __restrict__ Mrow, u16* __restrict__ Wi_bf) {
  const int wg = blockIdx.x, t = threadIdx.x;
  if (wg < 128) {
    const int idx = wg * 256 + t;          // 0..32767
    const int cout = idx >> 9;             // 0..63
    const int k = idx & 511;               // dir*128 + d
    float s = 0.f;
    for (int d = 0; d < 128; ++d) s = fmaf(Wo[cout * 128 + d], Wf[d * 512 + k], s);
    const int dir = k >> 7, dm = k & 127;
    Mrow[(dir * 64 + cout) * 128 + dm] = f2bf(s);
  } else if (wg == 128) {
    if (t < 128) A_t[t] = tanhf(A_param[t]);
    if (t < 64) {
      float s = bo[t];
      for (int d = 0; d < 128; ++d) s = fmaf(Wo[t * 128 + d], bf_[d], s);
      beff[t] = s;
    }
  } else {
#pragma unroll
    for (int k = 0; k < 32; ++k) {
      const int i = t + k * 256;
      Wi_bf[i] = f2bf(Wi[i]);
    }
  }
}

extern __shared__ char smem[];

// ---- Chunked scan (4 chunks x 32), prescaled input (B*x): h = A*h + xv. ----
template <bool REV>
DEVINL void scan_local(char* buf, int dp, int chunk, f32x2 A2) {
  f32x2 h = { 0.f, 0.f };
  const u32 cb = (u32)(dp * 4);
  const int s = chunk * 32;
  u32 nx[8];
#pragma unroll
  for (int j = 0; j < 8; ++j) {
    const int i = REV ? (127 - (s + j)) : (s + j);
    nx[j] = *(const u32*)(buf + i * 256 + (cb ^ ((u32)((i & 7) << 4))));
  }
  for (int ib = 0; ib < 32; ib += 8) {
    u32 cur[8];
#pragma unroll
    for (int j = 0; j < 8; ++j) cur[j] = nx[j];
    if (ib + 8 < 32) {
#pragma unroll
      for (int j = 0; j < 8; ++j) {
        const int i2 = s + ib + 8 + j;
        const int i = REV ? (127 - i2) : i2;
        nx[j] = *(const u32*)(buf + i * 256 + (cb ^ ((u32)((i & 7) << 4))));
      }
    }
#pragma unroll
    for (int j = 0; j < 8; ++j) {
      const int i2 = s + ib + j;
      const int i = REV ? (127 - i2) : i2;
      const f32x2 xv = { bf2f_lo(cur[j]), bf2f_hi(cur[j]) };
      h = A2 * h + xv;
      *(u32*)(buf + i * 256 + (cb ^ ((u32)((i & 7) << 4)))) = pack2(h.x, h.y);
    }
  }
}

// ---- Carry correction: h_i = l_i + A^{j+1} * C. ----
template <bool REV>
DEVINL void scan_fix(char* buf, int dp, int chunk, f32x2 A2) {
  if (chunk == 0) return;
  f32x2 q = A2;
#pragma unroll
  for (int k = 0; k < 5; ++k) q *= q;            // A^32
  const u32 cb = (u32)(dp * 4);
  f32x2 C = { 0.f, 0.f };
  for (int k = 0; k < chunk; ++k) {
    const int i2 = k * 32 + 31;
    const int i = REV ? (127 - i2) : i2;
    const u32 v = *(const u32*)(buf + i * 256 + (cb ^ ((u32)((i & 7) << 4))));
    const f32x2 xv = { bf2f_lo(v), bf2f_hi(v) };
    C = C * q + xv;
  }
  f32x2 p = A2;
  const int s = chunk * 32;
  u32 nx[8];
#pragma unroll
  for (int j = 0; j < 8; ++j) {
    const int i = REV ? (127 - (s + j)) : (s + j);
    nx[j] = *(const u32*)(buf + i * 256 + (cb ^ ((u32)((i & 7) << 4))));
  }
  for (int ib = 0; ib < 32; ib += 8) {
    u32 cur[8];
#pragma unroll
    for (int j = 0; j < 8; ++j) cur[j] = nx[j];
    if (ib + 8 < 32) {
#pragma unroll
      for (int j = 0; j < 8; ++j) {
        const int i2 = s + ib + 8 + j;
        const int i = REV ? (127 - i2) : i2;
        nx[j] = *(const u32*)(buf + i * 256 + (cb ^ ((u32)((i & 7) << 4))));
      }
    }
#pragma unroll
    for (int j = 0; j < 8; ++j) {
      const int i2 = s + ib + j;
      const int i = REV ? (127 - i2) : i2;
      const f32x2 xv = { bf2f_lo(cur[j]), bf2f_hi(cur[j]) };
      const f32x2 hv = p * C + xv;
      *(u32*)(buf + i * 256 + (cb ^ ((u32)((i & 7) << 4)))) = pack2(hv.x, hv.y);
      p *= A2;
    }
  }
}

// 512-thread scans: 2 dirs x 64 dp x 4 chunks.
DEVINL void run_scans512(char* bufA, char* bufB, int t, const float* __restrict__ A_t) {
  const int sub = t & 255, dp = sub & 63, chunk = sub >> 6, dir = t >> 8;
  const f32x2 a = *(const f32x2*)(A_t + dp * 2);
  char* sb = dir ? bufB : bufA;
  if (dir == 0) scan_local<false>(sb, dp, chunk, a);
  else          scan_local<true >(sb, dp, chunk, a);
  __syncthreads();
  if (dir == 0) scan_fix<false>(sb, dp, chunk, a);
  else          scan_fix<true >(sb, dp, chunk, a);
}

// Full-K combine for 512-thread blocks: acc2[2][2] over (dir_base, dir_base+1).
DEVINL void combine_full(const char* bufA, const char* bufB, const u16* __restrict__ Mrow,
                         int dir_base, int eh, int wq, int l15, int kg,
                         f32x4v (&acc2)[2][2]) {
#pragma unroll
  for (int dir = 0; dir < 2; ++dir) {
    const char* buf = dir ? bufB : bufA;
#pragma unroll
    for (int ks = 0; ks < 4; ++ks) {
      bf16x8 afr[2], bfr[2];
#pragma unroll
      for (int ct = 0; ct < 2; ++ct)
        afr[ct] = *(const bf16x8*)(Mrow + ((size_t)(dir_base + dir) * 64 + eh * 32 + ct * 16 + l15) * 128 + ks * 32 + kg * 8);
#pragma unroll
      for (int pt = 0; pt < 2; ++pt) {
        const int row = wq * 32 + pt * 16 + l15;
        bfr[pt] = *(const bf16x8*)(buf + row * 256 + ((u32)(ks * 64 + kg * 16) ^ ((u32)((row & 7) << 4))));
      }
#pragma unroll
      for (int ct = 0; ct < 2; ++ct)
#pragma unroll
        for (int pt = 0; pt < 2; ++pt)
          acc2[ct][pt] = __builtin_amdgcn_mfma_f32_16x16x32_bf16(bfr[pt], afr[ct], acc2[ct][pt], 0, 0, 0);
    }
  }
}

// acc -> OutS f32 [64 c][512B swz] (spans bufA+bufB), then stream to og[c][pos].
DEVINL void outs_epilogue512(const f32x4v (&acc2)[2][2], int eh, int wq, int l15, int kg,
                             int t, u16* __restrict__ og) {
#pragma unroll
  for (int ct = 0; ct < 2; ++ct)
#pragma unroll
    for (int pt = 0; pt < 2; ++pt) {
      const int c = eh * 32 + ct * 16 + l15;
      const int pos = wq * 32 + pt * 16 + kg * 4;
      *(f32x4v*)(smem + c * 512 + ((u32)(pos * 4) ^ ((u32)((c & 7) << 4)))) = acc2[ct][pt];
    }
  __syncthreads();
#pragma unroll
  for (int j = 0; j < 8; ++j) {
    const int i = t + j * 512;
    const int c = i >> 6, p2 = (i & 63) * 2;
    const f32x2 v = *(const f32x2*)(smem + c * 512 + ((u32)(p2 * 4) ^ ((u32)((c & 7) << 4))));
    *(u32*)(og + c * 128 + p2) = pack2(v.x, v.y);
  }
}

// ---------------- K_A: 512 threads, full-d: GEMM + h-scans + combine ----------------
// bid = b*128+h. Writes x2[bid][w][128d] (B-prescaled) and Shp[bid][c][w] (full).
__global__ __launch_bounds__(512, 4) void k_A(
    const float* __restrict__ F_in, const float* __restrict__ prior,
    const u16* __restrict__ Wi_bf, const float* __restrict__ bi,
    const float* __restrict__ Bp, const float* __restrict__ alpha_p,
    const float* __restrict__ A_t, const u16* __restrict__ Mrow,
    u16* __restrict__ x2, u16* __restrict__ Shp) {
  char* bufA = smem;            // 32 KB [128 w][256B] swz: FT -> Bx -> h_lr
  char* bufB = smem + 32768;    // 32 KB: Bx copy -> h_rl

  const int t = threadIdx.x;
  const int lane = t & 63, wv = t >> 6;           // wv 0..7
  const int l15 = lane & 15, kg = lane >> 4;
  const int bid = blockIdx.x, b = bid >> 7, h = bid & 127;
  const int wq = wv & 3, eh = wv >> 2;            // w-quarter, d/c-half

  // ---- P1: stage Fmod^T bf16 into bufA rows; FT swizzle folds row-bit-3 into
  //      column bit-7 (unused upper half of 256B rows) to break the 8-way
  //      same-(w&7) write conflict. P2 applies the same involution. ----
  {
    const int w = t & 127, ch = t >> 7;           // ch 0..3 -> 16 c each
    const float alpha = alpha_p[0];
    const float pv = prior[(b * 128 + h) * 128 + w];
    const float* Fb = F_in + ((size_t)b * 64 + ch * 16) * 16384 + h * 128 + w;
    const u32 sw = ((u32)((w & 7) << 4)) | (((u32)(w >> 3) & 1u) << 7);
    char* rowp = bufA + w * 256;
#pragma unroll
    for (int q = 0; q < 2; ++q) {
      float fv[8];
#pragma unroll
      for (int j = 0; j < 8; ++j) fv[j] = fmaf(alpha, pv, Fb[(q * 8 + j) * 16384]);
      uint4 pk;
      pk.x = pack2(fv[0], fv[1]); pk.y = pack2(fv[2], fv[3]);
      pk.z = pack2(fv[4], fv[5]); pk.w = pack2(fv[6], fv[7]);
      *(uint4*)(rowp + ((u32)(ch * 32 + q * 16) ^ sw)) = pk;
    }
  }
  __syncthreads();

  // ---- P2: Fmod B-frags (n=w, k=c 0..63) into regs (same extended swizzle) ----
  bf16x8 bF[2][2];   // [wj][ks]
#pragma unroll
  for (int wj = 0; wj < 2; ++wj)
#pragma unroll
    for (int ks = 0; ks < 2; ++ks) {
      const int row = wq * 32 + wj * 16 + l15;
      const u32 sw = ((u32)((row & 7) << 4)) | (((u32)(row >> 3) & 1u) << 7);
      bF[wj][ks] = *(const bf16x8*)(bufA + row * 256 + ((u32)(ks * 64 + kg * 16) ^ sw));
    }
  __syncthreads();

  // ---- P3: GEMM D[d][w] (d-half eh); prescale by B_d; Bx -> bufA + bufB ----
  {
    f32x4v acc[4][2];   // [dt][wj]
#pragma unroll
    for (int dt = 0; dt < 4; ++dt) {
      const f32x4 bv = *(const f32x4*)(bi + eh * 64 + dt * 16 + kg * 4);
      const f32x4v bvv = { bv.x, bv.y, bv.z, bv.w };
#pragma unroll
      for (int wj = 0; wj < 2; ++wj) acc[dt][wj] = bvv;
    }
#pragma unroll
    for (int ks = 0; ks < 2; ++ks)
#pragma unroll
      for (int dt = 0; dt < 4; ++dt) {
        const bf16x8 aWi = *(const bf16x8*)(Wi_bf + (eh * 64 + dt * 16 + l15) * 64 + ks * 32 + kg * 8);
        acc[dt][0] = __builtin_amdgcn_mfma_f32_16x16x32_bf16(aWi, bF[0][ks], acc[dt][0], 0, 0, 0);
        acc[dt][1] = __builtin_amdgcn_mfma_f32_16x16x32_bf16(aWi, bF[1][ks], acc[dt][1], 0, 0, 0);
      }
#pragma unroll
    for (int dt = 0; dt < 4; ++dt) {
      const f32x4 B4 = *(const f32x4*)(Bp + eh * 64 + dt * 16 + kg * 4);
      const f32x4v B4v = { B4.x, B4.y, B4.z, B4.w };
#pragma unroll
      for (int wj = 0; wj < 2; ++wj) {
        const f32x4v sv = acc[dt][wj] * B4v;
        const int w = wq * 32 + wj * 16 + l15;
        const int dl = eh * 64 + dt * 16 + kg * 4;
        uint2 pk;
        pk.x = pack2(sv[0], sv[1]);
        pk.y = pack2(sv[2], sv[3]);
        const u32 col = (u32)(dl * 2) ^ ((u32)((w & 7) << 4));
        *(uint2*)(bufA + w * 256 + col) = pk;
        *(uint2*)(bufB + w * 256 + col) = pk;
      }
    }
  }
  __syncthreads();

  // ---- P4: Bx -> global x2 (32 KB coalesced stream) ----
  {
    u16* xg = x2 + (size_t)bid * 16384;
#pragma unroll
    for (int j = 0; j < 4; ++j) {
      const int idx = t + j * 512;
      const int row = idx >> 4, q = idx & 15;
      const uint4 v = *(const uint4*)(bufA + row * 256 + ((u32)(q * 16) ^ ((u32)((row & 7) << 4))));
      *(uint4*)(xg + row * 128 + q * 8) = v;
    }
  }
  __syncthreads();

  // ---- P5: scans ----
  run_scans512(bufA, bufB, t, A_t);
  __syncthreads();

  // ---- P6-P8: combine + epilogue ----
  f32x4v acc2[2][2];
#pragma unroll
  for (int i = 0; i < 2; ++i)
#pragma unroll
    for (int j = 0; j < 2; ++j) acc2[i][j] = (f32x4v)0.f;
  combine_full(bufA, bufB, Mrow, 0, eh, wq, l15, kg, acc2);
  __syncthreads();
  outs_epilogue512(acc2, eh, wq, l15, kg, t, Shp + (size_t)bid * 8192);
}

// ---------------- K_B: 512 threads, full-d: v-scans + combine -> Svp[bid][c][h] (full) ----------------
// bid = b*128+w.
__global__ __launch_bounds__(512, 4) void k_B(
    const u16* __restrict__ x2,
    const float* __restrict__ A_t, const u16* __restrict__ Mrow,
    u16* __restrict__ Svp) {
  char* bufA = smem;            // 32 KB [128 h][256B] swz
  char* bufB = smem + 32768;

  const int t = threadIdx.x;
  const int lane = t & 63, wv = t >> 6;
  const int l15 = lane & 15, kg = lane >> 4;
  const int bid = blockIdx.x, b = bid >> 7, w = bid & 127;
  const int wq = wv & 3, eh = wv >> 2;

  // ---- P1: stage x rows (h-major, full 256B rows) into both buffers ----
#pragma unroll
  for (int j = 0; j < 4; ++j) {
    const int idx = t + j * 512;
    const int hh = idx >> 4, q = idx & 15;
    const uint4 v = *(const uint4*)(x2 + ((size_t)(b * 128 + hh) * 128 + w) * 128 + q * 8);
    const u32 col = (u32)(q * 16) ^ ((u32)((hh & 7) << 4));
    *(uint4*)(bufA + hh * 256 + col) = v;
    *(uint4*)(bufB + hh * 256 + col) = v;
  }
  __syncthreads();

  // ---- P2: scans (tb in bufA, bt in bufB) ----
  run_scans512(bufA, bufB, t, A_t);
  __syncthreads();

  // ---- P3-P5: combine (dirs 2,3) + epilogue ----
  f32x4v acc2[2][2];
#pragma unroll
  for (int i = 0; i < 2; ++i)
#pragma unroll
    for (int j = 0; j < 2; ++j) acc2[i][j] = (f32x4v)0.f;
  combine_full(bufA, bufB, Mrow, 2, eh, wq, l15, kg, acc2);
  __syncthreads();
  outs_epilogue512(acc2, eh, wq, l15, kg, t, Svp + (size_t)bid * 8192);
}

// ---------------- F: out = F_mod + gamma*(Sh + Sv^T + beff) ----------------
__global__ __launch_bounds__(256) void k_final(
    const float* __restrict__ F_in, const float* __restrict__ prior,
    const float* __restrict__ alpha_p, const float* __restrict__ gamma_p,
    const float* __restrict__ beff, const u16* __restrict__ Svp,
    const u16* __restrict__ Shp, float* __restrict__ out) {
  u16* Xu = (u16*)smem;
  const int t = threadIdx.x;
  const int bid = blockIdx.x, b = bid >> 6, c = bid & 63;
  const size_t base = (size_t)bid * 16384;   // (b,c) plane of out/F

  // stage Sv transposed via LDS: Xu[w][h], stride 132
  for (int i = t; i < 2048; i += 256) {
    const int w = i >> 4, q = i & 15;
    const uint4 a4 = *(const uint4*)(Svp + (size_t)(b * 128 + w) * 8192 + c * 128 + q * 8);
    u32* dst = (u32*)(Xu + w * 132 + q * 8);
    dst[0] = a4.x; dst[1] = a4.y; dst[2] = a4.z; dst[3] = a4.w;
  }
  __syncthreads();
  const float alpha = alpha_p[0], gamma = gamma_p[0];
  const float be = beff[c];
  for (int i = t; i < 2048; i += 256) {
    const int hh = i >> 4, w8 = (i & 15) * 8;
    const size_t off = base + hh * 128 + w8;
    const uint4 g0 = *(const uint4*)(Shp + (size_t)(b * 128 + hh) * 8192 + c * 128 + w8);
    const u16* p0 = (const u16*)&g0;
    const float* Fp = F_in + off;
    float* Op = out + off;
    const float* Pp = prior + (b * 128 + hh) * 128 + w8;
#pragma unroll
    for (int q = 0; q < 8; ++q) {
      const float sv = bf2f(Xu[(w8 + q) * 132 + hh]);
      Op[q] = Fp[q] + alpha * Pp[q] + gamma * (bf2f(p0[q]) + sv + be);
    }
  }
}

extern "C" void kernel_launch(void* const* d_in, const int* in_sizes, int n_in,
                              void* d_out, int out_size, void* d_ws, size_t ws_size,
                              hipStream_t stream) {
  const float* F_in   = (const float*)d_in[0];
  const float* prior  = (const float*)d_in[1];
  const float* Wi     = (const float*)d_in[2];
  const float* bi     = (const float*)d_in[3];
  const float* A_par  = (const float*)d_in[4];
  const float* B_par  = (const float*)d_in[5];
  const float* alpha  = (const float*)d_in[6];
  const float* gamma  = (const float*)d_in[7];
  const float* Wf     = (const float*)d_in[8];
  const float* bf_    = (const float*)d_in[9];
  const float* Wo     = (const float*)d_in[10];
  const float* bo     = (const float*)d_in[11];
  float* out = (float*)d_out;

  char* ws = (char*)d_ws;
  float* A_t   = (float*)ws;                        // 512 B
  float* beff  = (float*)(ws + 512);                // 256 B
  u16*   Mrow  = (u16*)(ws + 1024);                 // 64 KB: [4][64][128] bf16
  u16*   Wi_bf = (u16*)(ws + 66560);                // 16 KB: [128][64] bf16
  u16*   x2    = (u16*)(ws + 82944);                // 33.5 MB: [1024][128 w][128 d] (B-prescaled)
  u16*   Shp   = (u16*)(ws + 82944 + 33554432);     // 16.8 MB: [1024][64 c][128 w] (full)
  u16*   Svp   = (u16*)(ws + 82944 + 67108864);     // 16.8 MB: [1024][64 c][128 h] (full)

  hipFuncSetAttribute((const void*)k_A, hipFuncAttributeMaxDynamicSharedMemorySize, LDS_AB);
  hipFuncSetAttribute((const void*)k_B, hipFuncAttributeMaxDynamicSharedMemorySize, LDS_AB);

  k_pre  <<<130, 256, 0, stream>>>(Wf, Wo, bf_, bo, A_par, Wi, A_t, beff, Mrow, Wi_bf);
  k_A    <<<1024, 512, LDS_AB, stream>>>(F_in, prior, Wi_bf, bi, B_par, alpha, A_t, Mrow, x2, Shp);
  k_B    <<<1024, 512, LDS_AB, stream>>>(x2, A_t, Mrow, Svp);
  k_final<<<512, 256, LDS_X, stream>>>(F_in, prior, alpha, gamma, beff, Svp, Shp, out);
}